// Round 10
// baseline (235.348 us; speedup 1.0000x reference)
//
#include <hip/hip_runtime.h>

#define B_ 4
#define S_ 2048
#define D_ 1024
#define M_ 2048
#define J_ 8
#define H_ 16
#define HD_ 64
#define BH_ 64

typedef __attribute__((ext_vector_type(8))) short short8;
typedef __attribute__((ext_vector_type(4))) float f32x4;
typedef __attribute__((ext_vector_type(16))) float f32x16;

static __device__ __forceinline__ unsigned short f2bf(float x) {
  unsigned u = __float_as_uint(x);
  u = u + 0x7fffu + ((u >> 16) & 1u);
  return (unsigned short)(u >> 16);
}

static __device__ __forceinline__ unsigned cvtpk(float lo, float hi) {
  unsigned r;
  asm("v_cvt_pk_bf16_f32 %0, %1, %2" : "=v"(r) : "v"(lo), "v"(hi));
  return r;
}

static __device__ __forceinline__ void gload16(const void* g, void* l) {
  __builtin_amdgcn_global_load_lds(
      (const __attribute__((address_space(1))) unsigned*)g,
      (__attribute__((address_space(3))) unsigned*)l, 16, 0, 0);
}

// ---- memory @ W_out k-split partials (blocks 0..255) + WoT transpose (256..511)
__global__ __launch_bounds__(256) void k_mw_part(const float* __restrict__ memory,
                                                 const float* __restrict__ W_out,
                                                 const float* __restrict__ Wo,
                                                 float* __restrict__ part,
                                                 unsigned short* __restrict__ WoT) {
  if (blockIdx.x >= 256) {  // WoT[n][k] = bf16(Wo[k][n])
    int idx = blockIdx.x - 256;
    int kt = idx & 15, nt = idx >> 4;
    int t = threadIdx.x;
    __shared__ float tl[64][65];
    int r = t >> 6, c = t & 63;
#pragma unroll
    for (int i = 0; i < 16; ++i) {
      int row = i * 4 + r;
      tl[row][c] = Wo[(size_t)(kt * 64 + row) * D_ + nt * 64 + c];
    }
    __syncthreads();
#pragma unroll
    for (int i = 0; i < 16; ++i) {
      int nrow = i * 4 + r;
      WoT[(size_t)(nt * 64 + nrow) * D_ + kt * 64 + c] = f2bf(tl[c][nrow]);
    }
    return;
  }
  int nc = blockIdx.x >> 4, ks = blockIdx.x & 15;
  int t = threadIdx.x;
  int n = nc * 64 + (t & 63);
  int sub = t >> 6;
  int k0 = ks * 128 + sub * 32;
  float acc[J_];
#pragma unroll
  for (int j = 0; j < J_; ++j) acc[j] = 0.f;
  for (int k = k0; k < k0 + 32; ++k) {
    float wv = W_out[(size_t)k * D_ + n];
#pragma unroll
    for (int j = 0; j < J_; ++j) acc[j] += memory[j * M_ + k] * wv;
  }
  __shared__ float p4[4][J_][64];
#pragma unroll
  for (int j = 0; j < J_; ++j) p4[sub][j][t & 63] = acc[j];
  __syncthreads();
  if (t < 64) {
#pragma unroll
    for (int j = 0; j < J_; ++j)
      part[((size_t)ks * J_ + j) * D_ + nc * 64 + t] =
          p4[0][j][t] + p4[1][j][t] + p4[2][j][t] + p4[3][j][t];
  }
}

// G[9][1024] reduce + WaT[4][1024] = W_addr^T (cols 0..3 only)
__global__ __launch_bounds__(256) void k_mw_red(const float* __restrict__ part,
                                                const float* __restrict__ b_out,
                                                const float* __restrict__ W_addr,
                                                float* __restrict__ G,
                                                float* __restrict__ WaT) {
  if (blockIdx.x >= 36) {
    int q = blockIdx.x - 36;
    int c = threadIdx.x * 4;
#pragma unroll
    for (int e = 0; e < 4; ++e) WaT[q * D_ + c + e] = W_addr[(size_t)(c + e) * 16 + q];
    return;
  }
  int id = blockIdx.x * 256 + threadIdx.x;
  int j = id >> 10, n = id & 1023;
  if (j < 8) {
    float s = 0.f;
#pragma unroll
    for (int ks = 0; ks < 16; ++ks) s += part[((size_t)ks * J_ + j) * D_ + n];
    G[j * D_ + n] = s;
  } else {
    G[8 * D_ + n] = b_out[n];
  }
}

// G @ W_w, k-split partials: partq[3][4][9][1024]
__global__ __launch_bounds__(256) void k_mwq_part(const float* __restrict__ G,
                                                  const float* __restrict__ Wq,
                                                  const float* __restrict__ Wk,
                                                  const float* __restrict__ Wv,
                                                  float* __restrict__ partq) {
  int wi = blockIdx.x >> 6;
  int r = blockIdx.x & 63;
  int nc = r & 15, ks = r >> 4;
  const float* W = wi == 0 ? Wq : (wi == 1 ? Wk : Wv);
  int t = threadIdx.x;
  int n = nc * 64 + (t & 63);
  int sub = t >> 6;
  int k0 = ks * 256 + sub * 64;
  float acc[9];
#pragma unroll
  for (int j = 0; j < 9; ++j) acc[j] = 0.f;
  for (int k = k0; k < k0 + 64; ++k) {
    float wv = W[(size_t)k * D_ + n];
#pragma unroll
    for (int j = 0; j < 9; ++j) acc[j] += G[j * D_ + k] * wv;
  }
  __shared__ float p4[4][9][64];
#pragma unroll
  for (int j = 0; j < 9; ++j) p4[sub][j][t & 63] = acc[j];
  __syncthreads();
  if (t < 64) {
#pragma unroll
    for (int j = 0; j < 9; ++j)
      partq[(((size_t)wi * 4 + ks) * 9 + j) * D_ + nc * 64 + t] =
          p4[0][j][t] + p4[1][j][t] + p4[2][j][t] + p4[3][j][t];
  }
}

// reduce partials; fold bias into row 8 (no scaling — k_attn applies K1)
__global__ __launch_bounds__(256) void k_mwq_red(const float* __restrict__ partq,
                                                 const float* __restrict__ bq,
                                                 const float* __restrict__ bk,
                                                 const float* __restrict__ bv,
                                                 float* __restrict__ Hq,
                                                 float* __restrict__ Hk,
                                                 float* __restrict__ Hv) {
  int id = blockIdx.x * 256 + threadIdx.x;
  int wi = id / 9216;
  int rem = id - wi * 9216;
  int j = rem >> 10, n = rem & 1023;
  float s = 0.f;
#pragma unroll
  for (int ks = 0; ks < 4; ++ks)
    s += partq[(((size_t)wi * 4 + ks) * 9 + j) * D_ + n];
  if (j == 8) s += wi == 0 ? bq[n] : (wi == 1 ? bk[n] : bv[n]);
  float* Hh = wi == 0 ? Hq : (wi == 1 ? Hk : Hv);
  Hh[j * D_ + n] = s;
}

// wave-per-token QKV, fully coalesced reads (lane l: float4 at e*256+l*4).
// H* blended from global (L2-resident); bias pre-folded into row 8.
__global__ __launch_bounds__(256) void k_qkv(
    const float* __restrict__ query, const float* __restrict__ WaT,
    const float* __restrict__ b_addr, const float* __restrict__ Hq,
    const float* __restrict__ Hk, const float* __restrict__ Hv,
    unsigned short* __restrict__ Qg, unsigned short* __restrict__ Kg,
    unsigned short* __restrict__ Vg) {
  int w = threadIdx.x >> 6, l = threadIdx.x & 63;
  int tk = blockIdx.x * 4 + w;
  int b = tk >> 11, s = tk & (S_ - 1);
  const float* qrow = query + (size_t)tk * D_;
  float th0 = 0.f, th1 = 0.f, th2 = 0.f, th3 = 0.f;
#pragma unroll
  for (int e = 0; e < 4; ++e) {
    float4 qv = *(const float4*)(qrow + e * 256 + l * 4);
    float4 w0 = *(const float4*)(WaT + 0 * D_ + e * 256 + l * 4);
    float4 w1 = *(const float4*)(WaT + 1 * D_ + e * 256 + l * 4);
    float4 w2 = *(const float4*)(WaT + 2 * D_ + e * 256 + l * 4);
    float4 w3 = *(const float4*)(WaT + 3 * D_ + e * 256 + l * 4);
    th0 += qv.x * w0.x + qv.y * w0.y + qv.z * w0.z + qv.w * w0.w;
    th1 += qv.x * w1.x + qv.y * w1.y + qv.z * w1.z + qv.w * w1.w;
    th2 += qv.x * w2.x + qv.y * w2.y + qv.z * w2.z + qv.w * w2.w;
    th3 += qv.x * w3.x + qv.y * w3.y + qv.z * w3.z + qv.w * w3.w;
  }
#pragma unroll
  for (int off = 32; off; off >>= 1) {
    th0 += __shfl_xor(th0, off);
    th1 += __shfl_xor(th1, off);
    th2 += __shfl_xor(th2, off);
    th3 += __shfl_xor(th3, off);
  }
  float thv[4] = {th0 + b_addr[0], th1 + b_addr[1], th2 + b_addr[2],
                  th3 + b_addr[3]};
  float p[4];
#pragma unroll
  for (int q = 0; q < 4; ++q) {
    float sh = __sinf(thv[q] * 0.5f);
    p[q] = thv[q] > 0.f ? sh * sh : 0.f;
  }
  float sc[8];
  float mx = -1e30f;
#pragma unroll
  for (int j = 0; j < 8; ++j) {
    float v = 0.f;
#pragma unroll
    for (int q = 0; q < 4; ++q) v += ((j >> q) & 1) ? p[q] : 1.f - p[q];
    sc[j] = v;
    mx = fmaxf(mx, v);
  }
  float sum = 0.f;
#pragma unroll
  for (int j = 0; j < 8; ++j) {
    sc[j] = __expf(sc[j] - mx);
    sum += sc[j];
  }
  float inv = 1.f / sum;
  float a[8];
#pragma unroll
  for (int j = 0; j < 8; ++j) a[j] = sc[j] * inv;

  const float* Hs[3] = {Hq, Hk, Hv};
  unsigned short* os[3] = {Qg, Kg, Vg};
#pragma unroll
  for (int k = 0; k < 4; ++k) {
    int n0 = k * 256 + l * 4;
    int hh = n0 >> 6, d = n0 & 63;
    size_t obase = ((size_t)(b * H_ + hh) * S_ + s) * HD_ + d;
#pragma unroll
    for (int wi = 0; wi < 3; ++wi) {
      const float* Hh = Hs[wi];
      float4 accv = *(const float4*)(Hh + 8 * D_ + n0);  // bias pre-folded
#pragma unroll
      for (int j = 0; j < 8; ++j) {
        float4 hv = *(const float4*)(Hh + j * D_ + n0);
        accv.x += a[j] * hv.x;
        accv.y += a[j] * hv.y;
        accv.z += a[j] * hv.z;
        accv.w += a[j] * hv.w;
      }
      uint2 pk;
      pk.x = (unsigned)f2bf(accv.x) | ((unsigned)f2bf(accv.y) << 16);
      pk.y = (unsigned)f2bf(accv.z) | ((unsigned)f2bf(accv.w) << 16);
      *(uint2*)(os[wi] + obase) = pk;
    }
  }
}

// V (bh,s,d) -> Vt (bh,d,s)
__global__ __launch_bounds__(256) void k_vt(const unsigned short* __restrict__ Vg,
                                            unsigned short* __restrict__ Vtg) {
  int st = blockIdx.x & 31, bh = blockIdx.x >> 5;
  int t = threadIdx.x;
  __shared__ unsigned short tl[64][65];
  int rr = t >> 3, c8 = t & 7;
#pragma unroll
  for (int p = 0; p < 2; ++p) {
    int s = p * 32 + rr;
    uint4 v = *(const uint4*)(Vg + ((size_t)bh * S_ + st * 64 + s) * HD_ + c8 * 8);
    const unsigned short* pv = (const unsigned short*)&v;
#pragma unroll
    for (int j = 0; j < 8; ++j) tl[s][c8 * 8 + j] = pv[j];
  }
  __syncthreads();
#pragma unroll
  for (int p = 0; p < 2; ++p) {
    int d = p * 32 + rr;
    unsigned short o[8];
#pragma unroll
    for (int j = 0; j < 8; ++j) o[j] = tl[c8 * 8 + j][d];
    *(uint4*)(Vtg + ((size_t)bh * HD_ + d) * S_ + st * 64 + c8 * 8) = *(const uint4*)o;
  }
}

// flash attention: swapped-operand 32x32, in-block KV-split, fixed-max softmax,
// lsum via ones-MFMA (denominator = ones^T · P on the matrix pipe).
__global__ __launch_bounds__(512, 4) void k_attn(
    const unsigned short* __restrict__ Qg, const unsigned short* __restrict__ Kg,
    const unsigned short* __restrict__ Vtg, unsigned short* __restrict__ ctxg) {
  int id = blockIdx.x;  // 1024 blocks
  int xcd = id & 7;
  int qt = (id >> 3) & 15;
  int bh = xcd * 8 + (id >> 7);  // 8 heads per XCD -> K/V 4MB = one L2
  int t = threadIdx.x;
  int w = t >> 6, l = t & 63;
  int q31 = l & 31, h = l >> 5;
  int g = w >> 2;  // kv-half

  __shared__ __align__(16) unsigned short lds[32768];

  int q0 = qt * 128;
  const unsigned short* qp = Qg + ((size_t)bh * S_ + q0 + (w & 3) * 32 + q31) * HD_;
  short8 qf0 = *(const short8*)(qp + 0 + h * 8);
  short8 qf1 = *(const short8*)(qp + 16 + h * 8);
  short8 qf2 = *(const short8*)(qp + 32 + h * 8);
  short8 qf3 = *(const short8*)(qp + 48 + h * 8);

  short8 onesv;
#pragma unroll
  for (int e = 0; e < 8; ++e) onesv[e] = (short)0x3F80;  // bf16 1.0

  f32x16 accO0 = {}, accO1 = {}, accL = {};

  const unsigned short* kgb = Kg + (size_t)bh * S_ * HD_;
  const unsigned short* vtb = Vtg + (size_t)bh * HD_ * S_;
  int wg = w & 3;
  int rowK = l >> 3, gsl = l & 7;
  int srcg = gsl ^ rowK;

  {
    unsigned short* sKd = lds + g * 8192;
    unsigned short* sVd = sKd + 4096;
#pragma unroll
    for (int cc = 0; cc < 2; ++cc) {
      int c = wg * 2 + cc;
      int rr = c * 8 + rowK;
      gload16(kgb + ((size_t)(g * 1024 + rr)) * HD_ + srcg * 8, sKd + c * 512);
      gload16(vtb + (size_t)rr * S_ + g * 1024 + srcg * 8, sVd + c * 512);
    }
  }
  __syncthreads();

  const float K1 = 0.125f * 1.44269504f;
  const float M2 = 28.8539008f;  // 20 * log2(e): fixed softmax shift

  for (int it = 0; it < 16; ++it) {
    if (it < 15) {
      int kvn = g * 1024 + (it + 1) * 64;
      unsigned short* sKd = lds + ((it + 1) & 1) * 16384 + g * 8192;
      unsigned short* sVd = sKd + 4096;
#pragma unroll
      for (int cc = 0; cc < 2; ++cc) {
        int c = wg * 2 + cc;
        int rr = c * 8 + rowK;
        gload16(kgb + (size_t)(kvn + rr) * HD_ + srcg * 8, sKd + c * 512);
        gload16(vtb + (size_t)rr * S_ + kvn + srcg * 8, sVd + c * 512);
      }
    }
    unsigned short* sK = lds + (it & 1) * 16384 + g * 8192;
    unsigned short* sVt = sK + 4096;

    // QK^T: accS[half][r] = S'[kv][q = l&31]
    f32x16 accS0 = {}, accS1 = {};
    __builtin_amdgcn_s_setprio(1);
#pragma unroll
    for (int ds = 0; ds < 4; ++ds) {
      short8 qq = ds == 0 ? qf0 : ds == 1 ? qf1 : ds == 2 ? qf2 : qf3;
      {
        int row = q31;
        int gk = (ds * 2 + h) ^ (row & 7);
        short8 kf = *(const short8*)(sK + row * 64 + gk * 8);
        accS0 = __builtin_amdgcn_mfma_f32_32x32x16_bf16(kf, qq, accS0, 0, 0, 0);
      }
      {
        int row = 32 + q31;
        int gk = (ds * 2 + h) ^ (row & 7);
        short8 kf = *(const short8*)(sK + row * 64 + gk * 8);
        accS1 = __builtin_amdgcn_mfma_f32_32x32x16_bf16(kf, qq, accS1, 0, 0, 0);
      }
    }
    __builtin_amdgcn_s_setprio(0);

    // fixed-max softmax: P = exp2(S*K1 - M2); no VALU sum (done via ones-MFMA)
#pragma unroll
    for (int r = 0; r < 16; ++r) {
      accS0[r] = __builtin_exp2f(accS0[r] * K1 - M2);
      accS1[r] = __builtin_exp2f(accS1[r] * K1 - M2);
    }

    // P -> bf16 B-fragments
    short8 pb[4];
#pragma unroll
    for (int ks = 0; ks < 4; ++ks) {
      const int r0 = 8 * (ks & 1);
      float v0, v1, v2, v3, v4, v5, v6, v7;
      if (ks < 2) {
        v0 = accS0[r0 + 0]; v1 = accS0[r0 + 1]; v2 = accS0[r0 + 2]; v3 = accS0[r0 + 3];
        v4 = accS0[r0 + 4]; v5 = accS0[r0 + 5]; v6 = accS0[r0 + 6]; v7 = accS0[r0 + 7];
      } else {
        v0 = accS1[r0 + 0]; v1 = accS1[r0 + 1]; v2 = accS1[r0 + 2]; v3 = accS1[r0 + 3];
        v4 = accS1[r0 + 4]; v5 = accS1[r0 + 5]; v6 = accS1[r0 + 6]; v7 = accS1[r0 + 7];
      }
      unsigned X0 = cvtpk(v0, v1), X1 = cvtpk(v2, v3);
      unsigned Y0 = cvtpk(v4, v5), Y1 = cvtpk(v6, v7);
      union { unsigned u[4]; short8 s8; } uu;
#if __has_builtin(__builtin_amdgcn_permlane32_swap)
      typedef __attribute__((ext_vector_type(2))) unsigned uint2v;
      uint2v r02 = __builtin_amdgcn_permlane32_swap(X0, Y0, false, false);
      uint2v r13 = __builtin_amdgcn_permlane32_swap(X1, Y1, false, false);
      uu.u[0] = r02[0]; uu.u[1] = r13[0]; uu.u[2] = r02[1]; uu.u[3] = r13[1];
#else
      unsigned tX0 = __shfl_xor(X0, 32), tX1 = __shfl_xor(X1, 32);
      unsigned tY0 = __shfl_xor(Y0, 32), tY1 = __shfl_xor(Y1, 32);
      uu.u[0] = h ? tY0 : X0;
      uu.u[1] = h ? tY1 : X1;
      uu.u[2] = h ? Y0 : tX0;
      uu.u[3] = h ? Y1 : tX1;
#endif
      pb[ks] = uu.s8;
    }

    // PV + lsum-MFMA (ones^T . P)
    __builtin_amdgcn_s_setprio(1);
    {
      int row = q31;
      int rs = row & 7;
#pragma unroll
      for (int ks = 0; ks < 4; ++ks) {
        int gv = (ks * 2 + h) ^ rs;
        short8 vf = *(const short8*)(sVt + row * 64 + gv * 8);
        accO0 = __builtin_amdgcn_mfma_f32_32x32x16_bf16(vf, pb[ks], accO0, 0, 0, 0);
        accL = __builtin_amdgcn_mfma_f32_32x32x16_bf16(onesv, pb[ks], accL, 0, 0, 0);
      }
    }
    {
      int row = 32 + q31;
      int rs = row & 7;
#pragma unroll
      for (int ks = 0; ks < 4; ++ks) {
        int gv = (ks * 2 + h) ^ rs;
        short8 vf = *(const short8*)(sVt + row * 64 + gv * 8);
        accO1 = __builtin_amdgcn_mfma_f32_32x32x16_bf16(vf, pb[ks], accO1, 0, 0, 0);
      }
    }
    __builtin_amdgcn_s_setprio(0);

    __syncthreads();
  }

  float lt = accL[0];  // full kv-group denominator (all rows of accL identical)

  // in-block combine: waves 4-7 hand (lsum, unnormalized accO) to 0-3
  if (g == 1) {
    unsigned* xO = (unsigned*)lds;  // [4][64][17] u32
    int base = ((w & 3) * 64 + l) * 17;
#pragma unroll
    for (int j = 0; j < 8; ++j) xO[base + j] = cvtpk(accO0[2 * j], accO0[2 * j + 1]);
#pragma unroll
    for (int j = 0; j < 8; ++j) xO[base + 8 + j] = cvtpk(accO1[2 * j], accO1[2 * j + 1]);
    float* xml = (float*)(lds + 8704);
    if (h == 0) xml[(w & 3) * 32 + q31] = lt;
  }
  __syncthreads();
  float inv = 0.f;
  if (g == 0) {
    unsigned* xO = (unsigned*)lds;
    float* xml = (float*)(lds + 8704);
    int base = (w * 64 + l) * 17;
    inv = 1.f / (lt + xml[w * 32 + q31]);
#pragma unroll
    for (int j = 0; j < 8; ++j) {
      unsigned wd = xO[base + j];
      accO0[2 * j] += __uint_as_float(wd << 16);
      accO0[2 * j + 1] += __uint_as_float(wd & 0xffff0000u);
    }
#pragma unroll
    for (int j = 0; j < 8; ++j) {
      unsigned wd = xO[base + 8 + j];
      accO1[2 * j] += __uint_as_float(wd << 16);
      accO1[2 * j + 1] += __uint_as_float(wd & 0xffff0000u);
    }
  }
  __syncthreads();
  if (g == 0) {
    int row = w * 32 + q31;
    int swz = (q31 & 7) << 3;
#pragma unroll
    for (int r = 0; r < 16; ++r) {
      int dl = (r & 3) + 8 * (r >> 2) + 4 * h;
      lds[row * 64 + (dl ^ swz)] = f2bf(accO0[r] * inv);
      lds[row * 64 + ((32 + dl) ^ swz)] = f2bf(accO1[r] * inv);
    }
  }
  __syncthreads();
  int b = bh >> 4, head = bh & 15;
#pragma unroll
  for (int j = 0; j < 2; ++j) {
    int slot = t + j * 512;
    int row = slot >> 3, gg = slot & 7;
    uint4 vv = *(const uint4*)(lds + row * 64 + ((gg ^ (row & 7)) * 8));
    *(uint4*)(ctxg + ((size_t)(b * S_ + q0 + row)) * D_ + head * HD_ + gg * 8) = vv;
  }
}

// out[8192,1024] = ctx @ Wo + bo  (staging via global_load_lds, rule #21)
__global__ __launch_bounds__(256) void k_out(const unsigned short* __restrict__ Ag,
                                             const unsigned short* __restrict__ Btg,
                                             const float* __restrict__ bo,
                                             float* __restrict__ out) {
  int mt = blockIdx.x;
  int nt = blockIdx.y;
  int t = threadIdx.x;
  int w = t >> 6, l = t & 63;
  int l15 = l & 15, l4 = l >> 4;
  int wr = w >> 1, wc = w & 1;
  __shared__ __align__(16) unsigned short sA[128 * 64];
  __shared__ __align__(16) unsigned short sB[128 * 64];
  f32x4 acc[4][4];
#pragma unroll
  for (int mm = 0; mm < 4; ++mm)
#pragma unroll
    for (int nn = 0; nn < 4; ++nn) acc[mm][nn] = (f32x4){0.f, 0.f, 0.f, 0.f};
  int srow = t >> 3, gsl = t & 7;
  int srcg = gsl ^ (srow & 7);  // inverse-swizzled source granule
  for (int kt = 0; kt < 16; ++kt) {
    int k0 = kt * 64;
    __syncthreads();
#pragma unroll
    for (int p = 0; p < 4; ++p) {
      int row = p * 32 + srow;
      gload16(Ag + (size_t)(mt * 128 + row) * D_ + k0 + srcg * 8,
              sA + (p * 256 + t) * 8);
      gload16(Btg + (size_t)(nt * 128 + row) * D_ + k0 + srcg * 8,
              sB + (p * 256 + t) * 8);
    }
    __syncthreads();
    short8 a[4][2];
#pragma unroll
    for (int mm = 0; mm < 4; ++mm) {
      int row = wr * 64 + mm * 16 + l15;
      int sw = (row & 7) << 3;
      a[mm][0] = *(const short8*)(sA + row * 64 + ((l4 * 8) ^ sw));
      a[mm][1] = *(const short8*)(sA + row * 64 + ((32 + l4 * 8) ^ sw));
    }
#pragma unroll
    for (int nn = 0; nn < 4; ++nn) {
      int row = wc * 64 + nn * 16 + l15;
      int sw = (row & 7) << 3;
      short8 b0 = *(const short8*)(sB + row * 64 + ((l4 * 8) ^ sw));
      short8 b1 = *(const short8*)(sB + row * 64 + ((32 + l4 * 8) ^ sw));
#pragma unroll
      for (int mm = 0; mm < 4; ++mm) {
        acc[mm][nn] = __builtin_amdgcn_mfma_f32_16x16x32_bf16(a[mm][0], b0, acc[mm][nn], 0, 0, 0);
        acc[mm][nn] = __builtin_amdgcn_mfma_f32_16x16x32_bf16(a[mm][1], b1, acc[mm][nn], 0, 0, 0);
      }
    }
  }
#pragma unroll
  for (int mm = 0; mm < 4; ++mm) {
#pragma unroll
    for (int r = 0; r < 4; ++r) {
      int mrow = mt * 128 + wr * 64 + mm * 16 + l4 * 4 + r;
      float* orow = out + (size_t)mrow * D_ + nt * 128 + wc * 64;
#pragma unroll
      for (int nn = 0; nn < 4; ++nn) {
        int n = nn * 16 + l15;
        orow[n] = acc[mm][nn][r] + bo[nt * 128 + wc * 64 + n];
      }
    }
  }
}

extern "C" void kernel_launch(void* const* d_in, const int* in_sizes, int n_in,
                              void* d_out, int out_size, void* d_ws, size_t ws_size,
                              hipStream_t stream) {
  const float* query = (const float*)d_in[0];
  const float* W_addr = (const float*)d_in[1];
  const float* b_addr = (const float*)d_in[2];
  const float* memory = (const float*)d_in[3];
  const float* W_out = (const float*)d_in[4];
  const float* b_out = (const float*)d_in[5];
  const float* Wq = (const float*)d_in[6];
  const float* bq = (const float*)d_in[7];
  const float* Wk = (const float*)d_in[8];
  const float* bk = (const float*)d_in[9];
  const float* Wv = (const float*)d_in[10];
  const float* bv = (const float*)d_in[11];
  const float* Wo = (const float*)d_in[12];
  const float* bo = (const float*)d_in[13];
  float* out = (float*)d_out;

  char* ws = (char*)d_ws;
  size_t off = 0;
  auto alloc = [&](size_t bytes) {
    char* p = ws + off;
    off = (off + bytes + 255) & ~(size_t)255;
    return p;
  };
  float* G = (float*)alloc(9 * D_ * sizeof(float));
  float* HqA = (float*)alloc(9 * D_ * sizeof(float));
  float* HkA = (float*)alloc(9 * D_ * sizeof(float));
  float* HvA = (float*)alloc(9 * D_ * sizeof(float));
  float* WaT = (float*)alloc(4 * D_ * sizeof(float));
  float* partmw = (float*)alloc(16 * J_ * D_ * sizeof(float));
  float* partq = (float*)alloc(3 * 4 * 9 * D_ * sizeof(float));
  unsigned short* WoT = (unsigned short*)alloc((size_t)D_ * D_ * 2);
  unsigned short* Vg = (unsigned short*)alloc((size_t)BH_ * S_ * HD_ * 2);
  unsigned short* Vtg = (unsigned short*)alloc((size_t)BH_ * S_ * HD_ * 2);
  unsigned short* Qg = (unsigned short*)d_out;
  unsigned short* Kg = Qg + (size_t)BH_ * S_ * HD_;
  unsigned short* ctx = Vg;

  k_mw_part<<<512, 256, 0, stream>>>(memory, W_out, Wo, partmw, WoT);
  k_mw_red<<<40, 256, 0, stream>>>(partmw, b_out, W_addr, G, WaT);
  k_mwq_part<<<192, 256, 0, stream>>>(G, Wq, Wk, Wv, partq);
  k_mwq_red<<<108, 256, 0, stream>>>(partq, bq, bk, bv, HqA, HkA, HvA);
  k_qkv<<<B_ * S_ / 4, 256, 0, stream>>>(query, WaT, b_addr, HqA, HkA, HvA,
                                         Qg, Kg, Vg);
  k_vt<<<BH_ * 32, 256, 0, stream>>>(Vg, Vtg);
  k_attn<<<1024, 512, 0, stream>>>(Qg, Kg, Vtg, ctx);
  k_out<<<dim3(64, 8), 256, 0, stream>>>(ctx, WoT, bo, out);
}

// Round 11
// 229.617 us; speedup vs baseline: 1.0250x; 1.0250x over previous
//
#include <hip/hip_runtime.h>

#define B_ 4
#define S_ 2048
#define D_ 1024
#define M_ 2048
#define J_ 8
#define H_ 16
#define HD_ 64
#define BH_ 64

typedef __attribute__((ext_vector_type(8))) short short8;
typedef __attribute__((ext_vector_type(4))) float f32x4;
typedef __attribute__((ext_vector_type(16))) float f32x16;

static __device__ __forceinline__ unsigned short f2bf(float x) {
  unsigned u = __float_as_uint(x);
  u = u + 0x7fffu + ((u >> 16) & 1u);
  return (unsigned short)(u >> 16);
}

static __device__ __forceinline__ unsigned cvtpk(float lo, float hi) {
  unsigned r;
  asm("v_cvt_pk_bf16_f32 %0, %1, %2" : "=v"(r) : "v"(lo), "v"(hi));
  return r;
}

static __device__ __forceinline__ void gload16(const void* g, void* l) {
  __builtin_amdgcn_global_load_lds(
      (const __attribute__((address_space(1))) unsigned*)g,
      (__attribute__((address_space(3))) unsigned*)l, 16, 0, 0);
}

// ---- memory @ W_out k-split partials (blocks 0..255) + WoT transpose (256..511)
__global__ __launch_bounds__(256) void k_mw_part(const float* __restrict__ memory,
                                                 const float* __restrict__ W_out,
                                                 const float* __restrict__ Wo,
                                                 float* __restrict__ part,
                                                 unsigned short* __restrict__ WoT) {
  if (blockIdx.x >= 256) {  // WoT[n][k] = bf16(Wo[k][n])
    int idx = blockIdx.x - 256;
    int kt = idx & 15, nt = idx >> 4;
    int t = threadIdx.x;
    __shared__ float tl[64][65];
    int r = t >> 6, c = t & 63;
#pragma unroll
    for (int i = 0; i < 16; ++i) {
      int row = i * 4 + r;
      tl[row][c] = Wo[(size_t)(kt * 64 + row) * D_ + nt * 64 + c];
    }
    __syncthreads();
#pragma unroll
    for (int i = 0; i < 16; ++i) {
      int nrow = i * 4 + r;
      WoT[(size_t)(nt * 64 + nrow) * D_ + kt * 64 + c] = f2bf(tl[c][nrow]);
    }
    return;
  }
  int nc = blockIdx.x >> 4, ks = blockIdx.x & 15;
  int t = threadIdx.x;
  int n = nc * 64 + (t & 63);
  int sub = t >> 6;
  int k0 = ks * 128 + sub * 32;
  float acc[J_];
#pragma unroll
  for (int j = 0; j < J_; ++j) acc[j] = 0.f;
  for (int k = k0; k < k0 + 32; ++k) {
    float wv = W_out[(size_t)k * D_ + n];
#pragma unroll
    for (int j = 0; j < J_; ++j) acc[j] += memory[j * M_ + k] * wv;
  }
  __shared__ float p4[4][J_][64];
#pragma unroll
  for (int j = 0; j < J_; ++j) p4[sub][j][t & 63] = acc[j];
  __syncthreads();
  if (t < 64) {
#pragma unroll
    for (int j = 0; j < J_; ++j)
      part[((size_t)ks * J_ + j) * D_ + nc * 64 + t] =
          p4[0][j][t] + p4[1][j][t] + p4[2][j][t] + p4[3][j][t];
  }
}

// G[9][1024] reduce + WaT[4][1024] = W_addr^T (cols 0..3 only)
__global__ __launch_bounds__(256) void k_mw_red(const float* __restrict__ part,
                                                const float* __restrict__ b_out,
                                                const float* __restrict__ W_addr,
                                                float* __restrict__ G,
                                                float* __restrict__ WaT) {
  if (blockIdx.x >= 36) {
    int q = blockIdx.x - 36;
    int c = threadIdx.x * 4;
#pragma unroll
    for (int e = 0; e < 4; ++e) WaT[q * D_ + c + e] = W_addr[(size_t)(c + e) * 16 + q];
    return;
  }
  int id = blockIdx.x * 256 + threadIdx.x;
  int j = id >> 10, n = id & 1023;
  if (j < 8) {
    float s = 0.f;
#pragma unroll
    for (int ks = 0; ks < 16; ++ks) s += part[((size_t)ks * J_ + j) * D_ + n];
    G[j * D_ + n] = s;
  } else {
    G[8 * D_ + n] = b_out[n];
  }
}

// G @ W_w, k-split partials: partq[3][4][9][1024]
__global__ __launch_bounds__(256) void k_mwq_part(const float* __restrict__ G,
                                                  const float* __restrict__ Wq,
                                                  const float* __restrict__ Wk,
                                                  const float* __restrict__ Wv,
                                                  float* __restrict__ partq) {
  int wi = blockIdx.x >> 6;
  int r = blockIdx.x & 63;
  int nc = r & 15, ks = r >> 4;
  const float* W = wi == 0 ? Wq : (wi == 1 ? Wk : Wv);
  int t = threadIdx.x;
  int n = nc * 64 + (t & 63);
  int sub = t >> 6;
  int k0 = ks * 256 + sub * 64;
  float acc[9];
#pragma unroll
  for (int j = 0; j < 9; ++j) acc[j] = 0.f;
  for (int k = k0; k < k0 + 64; ++k) {
    float wv = W[(size_t)k * D_ + n];
#pragma unroll
    for (int j = 0; j < 9; ++j) acc[j] += G[j * D_ + k] * wv;
  }
  __shared__ float p4[4][9][64];
#pragma unroll
  for (int j = 0; j < 9; ++j) p4[sub][j][t & 63] = acc[j];
  __syncthreads();
  if (t < 64) {
#pragma unroll
    for (int j = 0; j < 9; ++j)
      partq[(((size_t)wi * 4 + ks) * 9 + j) * D_ + nc * 64 + t] =
          p4[0][j][t] + p4[1][j][t] + p4[2][j][t] + p4[3][j][t];
  }
}

// reduce partials; fold bias into row 8 (no scaling — k_attn applies K1)
__global__ __launch_bounds__(256) void k_mwq_red(const float* __restrict__ partq,
                                                 const float* __restrict__ bq,
                                                 const float* __restrict__ bk,
                                                 const float* __restrict__ bv,
                                                 float* __restrict__ Hq,
                                                 float* __restrict__ Hk,
                                                 float* __restrict__ Hv) {
  int id = blockIdx.x * 256 + threadIdx.x;
  int wi = id / 9216;
  int rem = id - wi * 9216;
  int j = rem >> 10, n = rem & 1023;
  float s = 0.f;
#pragma unroll
  for (int ks = 0; ks < 4; ++ks)
    s += partq[(((size_t)wi * 4 + ks) * 9 + j) * D_ + n];
  if (j == 8) s += wi == 0 ? bq[n] : (wi == 1 ? bk[n] : bv[n]);
  float* Hh = wi == 0 ? Hq : (wi == 1 ? Hk : Hv);
  Hh[j * D_ + n] = s;
}

// wave-per-token QKV, fully coalesced reads (lane l: float4 at e*256+l*4).
// H* blended from global (L2-resident); bias pre-folded into row 8.
__global__ __launch_bounds__(256) void k_qkv(
    const float* __restrict__ query, const float* __restrict__ WaT,
    const float* __restrict__ b_addr, const float* __restrict__ Hq,
    const float* __restrict__ Hk, const float* __restrict__ Hv,
    unsigned short* __restrict__ Qg, unsigned short* __restrict__ Kg,
    unsigned short* __restrict__ Vg) {
  int w = threadIdx.x >> 6, l = threadIdx.x & 63;
  int tk = blockIdx.x * 4 + w;
  int b = tk >> 11, s = tk & (S_ - 1);
  const float* qrow = query + (size_t)tk * D_;
  float th0 = 0.f, th1 = 0.f, th2 = 0.f, th3 = 0.f;
#pragma unroll
  for (int e = 0; e < 4; ++e) {
    float4 qv = *(const float4*)(qrow + e * 256 + l * 4);
    float4 w0 = *(const float4*)(WaT + 0 * D_ + e * 256 + l * 4);
    float4 w1 = *(const float4*)(WaT + 1 * D_ + e * 256 + l * 4);
    float4 w2 = *(const float4*)(WaT + 2 * D_ + e * 256 + l * 4);
    float4 w3 = *(const float4*)(WaT + 3 * D_ + e * 256 + l * 4);
    th0 += qv.x * w0.x + qv.y * w0.y + qv.z * w0.z + qv.w * w0.w;
    th1 += qv.x * w1.x + qv.y * w1.y + qv.z * w1.z + qv.w * w1.w;
    th2 += qv.x * w2.x + qv.y * w2.y + qv.z * w2.z + qv.w * w2.w;
    th3 += qv.x * w3.x + qv.y * w3.y + qv.z * w3.z + qv.w * w3.w;
  }
#pragma unroll
  for (int off = 32; off; off >>= 1) {
    th0 += __shfl_xor(th0, off);
    th1 += __shfl_xor(th1, off);
    th2 += __shfl_xor(th2, off);
    th3 += __shfl_xor(th3, off);
  }
  float thv[4] = {th0 + b_addr[0], th1 + b_addr[1], th2 + b_addr[2],
                  th3 + b_addr[3]};
  float p[4];
#pragma unroll
  for (int q = 0; q < 4; ++q) {
    float sh = __sinf(thv[q] * 0.5f);
    p[q] = thv[q] > 0.f ? sh * sh : 0.f;
  }
  float sc[8];
  float mx = -1e30f;
#pragma unroll
  for (int j = 0; j < 8; ++j) {
    float v = 0.f;
#pragma unroll
    for (int q = 0; q < 4; ++q) v += ((j >> q) & 1) ? p[q] : 1.f - p[q];
    sc[j] = v;
    mx = fmaxf(mx, v);
  }
  float sum = 0.f;
#pragma unroll
  for (int j = 0; j < 8; ++j) {
    sc[j] = __expf(sc[j] - mx);
    sum += sc[j];
  }
  float inv = 1.f / sum;
  float a[8];
#pragma unroll
  for (int j = 0; j < 8; ++j) a[j] = sc[j] * inv;

  const float* Hs[3] = {Hq, Hk, Hv};
  unsigned short* os[3] = {Qg, Kg, Vg};
#pragma unroll
  for (int k = 0; k < 4; ++k) {
    int n0 = k * 256 + l * 4;
    int hh = n0 >> 6, d = n0 & 63;
    size_t obase = ((size_t)(b * H_ + hh) * S_ + s) * HD_ + d;
#pragma unroll
    for (int wi = 0; wi < 3; ++wi) {
      const float* Hh = Hs[wi];
      float4 accv = *(const float4*)(Hh + 8 * D_ + n0);  // bias pre-folded
#pragma unroll
      for (int j = 0; j < 8; ++j) {
        float4 hv = *(const float4*)(Hh + j * D_ + n0);
        accv.x += a[j] * hv.x;
        accv.y += a[j] * hv.y;
        accv.z += a[j] * hv.z;
        accv.w += a[j] * hv.w;
      }
      uint2 pk;
      pk.x = (unsigned)f2bf(accv.x) | ((unsigned)f2bf(accv.y) << 16);
      pk.y = (unsigned)f2bf(accv.z) | ((unsigned)f2bf(accv.w) << 16);
      *(uint2*)(os[wi] + obase) = pk;
    }
  }
}

// V (bh,s,d) -> Vt (bh,d,s)
__global__ __launch_bounds__(256) void k_vt(const unsigned short* __restrict__ Vg,
                                            unsigned short* __restrict__ Vtg) {
  int st = blockIdx.x & 31, bh = blockIdx.x >> 5;
  int t = threadIdx.x;
  __shared__ unsigned short tl[64][65];
  int rr = t >> 3, c8 = t & 7;
#pragma unroll
  for (int p = 0; p < 2; ++p) {
    int s = p * 32 + rr;
    uint4 v = *(const uint4*)(Vg + ((size_t)bh * S_ + st * 64 + s) * HD_ + c8 * 8);
    const unsigned short* pv = (const unsigned short*)&v;
#pragma unroll
    for (int j = 0; j < 8; ++j) tl[s][c8 * 8 + j] = pv[j];
  }
  __syncthreads();
#pragma unroll
  for (int p = 0; p < 2; ++p) {
    int d = p * 32 + rr;
    unsigned short o[8];
#pragma unroll
    for (int j = 0; j < 8; ++j) o[j] = tl[c8 * 8 + j][d];
    *(uint4*)(Vtg + ((size_t)bh * HD_ + d) * S_ + st * 64 + c8 * 8) = *(const uint4*)o;
  }
}

// flash attention: swapped-operand 32x32, in-block KV-split, fixed-max softmax
// (r9-proven inner loop), dbuf + issue-early global_load_lds, 1 barrier/tile.
__global__ __launch_bounds__(512, 4) void k_attn(
    const unsigned short* __restrict__ Qg, const unsigned short* __restrict__ Kg,
    const unsigned short* __restrict__ Vtg, unsigned short* __restrict__ ctxg) {
  int id = blockIdx.x;  // 1024 blocks
  int xcd = id & 7;
  int qt = (id >> 3) & 15;
  int bh = xcd * 8 + (id >> 7);  // 8 heads per XCD -> K/V 4MB = one L2
  int t = threadIdx.x;
  int w = t >> 6, l = t & 63;
  int q31 = l & 31, h = l >> 5;
  int g = w >> 2;  // kv-half

  __shared__ __align__(16) unsigned short lds[32768];

  int q0 = qt * 128;
  const unsigned short* qp = Qg + ((size_t)bh * S_ + q0 + (w & 3) * 32 + q31) * HD_;
  short8 qf0 = *(const short8*)(qp + 0 + h * 8);
  short8 qf1 = *(const short8*)(qp + 16 + h * 8);
  short8 qf2 = *(const short8*)(qp + 32 + h * 8);
  short8 qf3 = *(const short8*)(qp + 48 + h * 8);

  f32x16 accO0 = {}, accO1 = {};
  float lsum = 0.f;

  const unsigned short* kgb = Kg + (size_t)bh * S_ * HD_;
  const unsigned short* vtb = Vtg + (size_t)bh * HD_ * S_;
  int wg = w & 3;
  int rowK = l >> 3, gsl = l & 7;
  int srcg = gsl ^ rowK;

  {
    unsigned short* sKd = lds + g * 8192;
    unsigned short* sVd = sKd + 4096;
#pragma unroll
    for (int cc = 0; cc < 2; ++cc) {
      int c = wg * 2 + cc;
      int rr = c * 8 + rowK;
      gload16(kgb + ((size_t)(g * 1024 + rr)) * HD_ + srcg * 8, sKd + c * 512);
      gload16(vtb + (size_t)rr * S_ + g * 1024 + srcg * 8, sVd + c * 512);
    }
  }
  __syncthreads();

  const float K1 = 0.125f * 1.44269504f;
  const float M2 = 28.8539008f;  // 20 * log2(e): fixed softmax shift

  for (int it = 0; it < 16; ++it) {
    if (it < 15) {
      int kvn = g * 1024 + (it + 1) * 64;
      unsigned short* sKd = lds + ((it + 1) & 1) * 16384 + g * 8192;
      unsigned short* sVd = sKd + 4096;
#pragma unroll
      for (int cc = 0; cc < 2; ++cc) {
        int c = wg * 2 + cc;
        int rr = c * 8 + rowK;
        gload16(kgb + (size_t)(kvn + rr) * HD_ + srcg * 8, sKd + c * 512);
        gload16(vtb + (size_t)rr * S_ + kvn + srcg * 8, sVd + c * 512);
      }
    }
    unsigned short* sK = lds + (it & 1) * 16384 + g * 8192;
    unsigned short* sVt = sK + 4096;

    // QK^T: accS[half][r] = S'[kv][q = l&31]
    f32x16 accS0 = {}, accS1 = {};
    __builtin_amdgcn_s_setprio(1);
#pragma unroll
    for (int ds = 0; ds < 4; ++ds) {
      short8 qq = ds == 0 ? qf0 : ds == 1 ? qf1 : ds == 2 ? qf2 : qf3;
      {
        int row = q31;
        int gk = (ds * 2 + h) ^ (row & 7);
        short8 kf = *(const short8*)(sK + row * 64 + gk * 8);
        accS0 = __builtin_amdgcn_mfma_f32_32x32x16_bf16(kf, qq, accS0, 0, 0, 0);
      }
      {
        int row = 32 + q31;
        int gk = (ds * 2 + h) ^ (row & 7);
        short8 kf = *(const short8*)(sK + row * 64 + gk * 8);
        accS1 = __builtin_amdgcn_mfma_f32_32x32x16_bf16(kf, qq, accS1, 0, 0, 0);
      }
    }
    __builtin_amdgcn_s_setprio(0);

    // fixed-max softmax: P = exp2(S*K1 - M2); lane-local lsum
    float ts = 0.f;
#pragma unroll
    for (int r = 0; r < 16; ++r) {
      float p0 = __builtin_exp2f(accS0[r] * K1 - M2);
      float p1 = __builtin_exp2f(accS1[r] * K1 - M2);
      accS0[r] = p0;
      accS1[r] = p1;
      ts += p0 + p1;
    }
    lsum += ts;

    // P -> bf16 B-fragments
    short8 pb[4];
#pragma unroll
    for (int ks = 0; ks < 4; ++ks) {
      const int r0 = 8 * (ks & 1);
      float v0, v1, v2, v3, v4, v5, v6, v7;
      if (ks < 2) {
        v0 = accS0[r0 + 0]; v1 = accS0[r0 + 1]; v2 = accS0[r0 + 2]; v3 = accS0[r0 + 3];
        v4 = accS0[r0 + 4]; v5 = accS0[r0 + 5]; v6 = accS0[r0 + 6]; v7 = accS0[r0 + 7];
      } else {
        v0 = accS1[r0 + 0]; v1 = accS1[r0 + 1]; v2 = accS1[r0 + 2]; v3 = accS1[r0 + 3];
        v4 = accS1[r0 + 4]; v5 = accS1[r0 + 5]; v6 = accS1[r0 + 6]; v7 = accS1[r0 + 7];
      }
      unsigned X0 = cvtpk(v0, v1), X1 = cvtpk(v2, v3);
      unsigned Y0 = cvtpk(v4, v5), Y1 = cvtpk(v6, v7);
      union { unsigned u[4]; short8 s8; } uu;
#if __has_builtin(__builtin_amdgcn_permlane32_swap)
      typedef __attribute__((ext_vector_type(2))) unsigned uint2v;
      uint2v r02 = __builtin_amdgcn_permlane32_swap(X0, Y0, false, false);
      uint2v r13 = __builtin_amdgcn_permlane32_swap(X1, Y1, false, false);
      uu.u[0] = r02[0]; uu.u[1] = r13[0]; uu.u[2] = r02[1]; uu.u[3] = r13[1];
#else
      unsigned tX0 = __shfl_xor(X0, 32), tX1 = __shfl_xor(X1, 32);
      unsigned tY0 = __shfl_xor(Y0, 32), tY1 = __shfl_xor(Y1, 32);
      uu.u[0] = h ? tY0 : X0;
      uu.u[1] = h ? tY1 : X1;
      uu.u[2] = h ? Y0 : tX0;
      uu.u[3] = h ? Y1 : tX1;
#endif
      pb[ks] = uu.s8;
    }

    // PV
    __builtin_amdgcn_s_setprio(1);
    {
      int row = q31;
      int rs = row & 7;
#pragma unroll
      for (int ks = 0; ks < 4; ++ks) {
        int gv = (ks * 2 + h) ^ rs;
        short8 vf = *(const short8*)(sVt + row * 64 + gv * 8);
        accO0 = __builtin_amdgcn_mfma_f32_32x32x16_bf16(vf, pb[ks], accO0, 0, 0, 0);
      }
    }
    {
      int row = 32 + q31;
      int rs = row & 7;
#pragma unroll
      for (int ks = 0; ks < 4; ++ks) {
        int gv = (ks * 2 + h) ^ rs;
        short8 vf = *(const short8*)(sVt + row * 64 + gv * 8);
        accO1 = __builtin_amdgcn_mfma_f32_32x32x16_bf16(vf, pb[ks], accO1, 0, 0, 0);
      }
    }
    __builtin_amdgcn_s_setprio(0);

    __syncthreads();
  }

  float lt = lsum + __shfl_xor(lsum, 32);

  // in-block combine: waves 4-7 hand (lsum, unnormalized accO) to 0-3
  if (g == 1) {
    unsigned* xO = (unsigned*)lds;  // [4][64][17] u32
    int base = ((w & 3) * 64 + l) * 17;
#pragma unroll
    for (int j = 0; j < 8; ++j) xO[base + j] = cvtpk(accO0[2 * j], accO0[2 * j + 1]);
#pragma unroll
    for (int j = 0; j < 8; ++j) xO[base + 8 + j] = cvtpk(accO1[2 * j], accO1[2 * j + 1]);
    float* xml = (float*)(lds + 8704);
    if (h == 0) xml[(w & 3) * 32 + q31] = lt;
  }
  __syncthreads();
  float inv = 0.f;
  if (g == 0) {
    unsigned* xO = (unsigned*)lds;
    float* xml = (float*)(lds + 8704);
    int base = (w * 64 + l) * 17;
    inv = 1.f / (lt + xml[w * 32 + q31]);
#pragma unroll
    for (int j = 0; j < 8; ++j) {
      unsigned wd = xO[base + j];
      accO0[2 * j] += __uint_as_float(wd << 16);
      accO0[2 * j + 1] += __uint_as_float(wd & 0xffff0000u);
    }
#pragma unroll
    for (int j = 0; j < 8; ++j) {
      unsigned wd = xO[base + 8 + j];
      accO1[2 * j] += __uint_as_float(wd << 16);
      accO1[2 * j + 1] += __uint_as_float(wd & 0xffff0000u);
    }
  }
  __syncthreads();
  if (g == 0) {
    int row = w * 32 + q31;
    int swz = (q31 & 7) << 3;
#pragma unroll
    for (int r = 0; r < 16; ++r) {
      int dl = (r & 3) + 8 * (r >> 2) + 4 * h;
      lds[row * 64 + (dl ^ swz)] = f2bf(accO0[r] * inv);
      lds[row * 64 + ((32 + dl) ^ swz)] = f2bf(accO1[r] * inv);
    }
  }
  __syncthreads();
  int b = bh >> 4, head = bh & 15;
#pragma unroll
  for (int j = 0; j < 2; ++j) {
    int slot = t + j * 512;
    int row = slot >> 3, gg = slot & 7;
    uint4 vv = *(const uint4*)(lds + row * 64 + ((gg ^ (row & 7)) * 8));
    *(uint4*)(ctxg + ((size_t)(b * S_ + q0 + row)) * D_ + head * HD_ + gg * 8) = vv;
  }
}

// out[8192,1024] = ctx @ Wo + bo  (staging via global_load_lds, rule #21)
__global__ __launch_bounds__(256) void k_out(const unsigned short* __restrict__ Ag,
                                             const unsigned short* __restrict__ Btg,
                                             const float* __restrict__ bo,
                                             float* __restrict__ out) {
  int mt = blockIdx.x;
  int nt = blockIdx.y;
  int t = threadIdx.x;
  int w = t >> 6, l = t & 63;
  int l15 = l & 15, l4 = l >> 4;
  int wr = w >> 1, wc = w & 1;
  __shared__ __align__(16) unsigned short sA[128 * 64];
  __shared__ __align__(16) unsigned short sB[128 * 64];
  f32x4 acc[4][4];
#pragma unroll
  for (int mm = 0; mm < 4; ++mm)
#pragma unroll
    for (int nn = 0; nn < 4; ++nn) acc[mm][nn] = (f32x4){0.f, 0.f, 0.f, 0.f};
  int srow = t >> 3, gsl = t & 7;
  int srcg = gsl ^ (srow & 7);  // inverse-swizzled source granule
  for (int kt = 0; kt < 16; ++kt) {
    int k0 = kt * 64;
    __syncthreads();
#pragma unroll
    for (int p = 0; p < 4; ++p) {
      int row = p * 32 + srow;
      gload16(Ag + (size_t)(mt * 128 + row) * D_ + k0 + srcg * 8,
              sA + (p * 256 + t) * 8);
      gload16(Btg + (size_t)(nt * 128 + row) * D_ + k0 + srcg * 8,
              sB + (p * 256 + t) * 8);
    }
    __syncthreads();
    short8 a[4][2];
#pragma unroll
    for (int mm = 0; mm < 4; ++mm) {
      int row = wr * 64 + mm * 16 + l15;
      int sw = (row & 7) << 3;
      a[mm][0] = *(const short8*)(sA + row * 64 + ((l4 * 8) ^ sw));
      a[mm][1] = *(const short8*)(sA + row * 64 + ((32 + l4 * 8) ^ sw));
    }
#pragma unroll
    for (int nn = 0; nn < 4; ++nn) {
      int row = wc * 64 + nn * 16 + l15;
      int sw = (row & 7) << 3;
      short8 b0 = *(const short8*)(sB + row * 64 + ((l4 * 8) ^ sw));
      short8 b1 = *(const short8*)(sB + row * 64 + ((32 + l4 * 8) ^ sw));
#pragma unroll
      for (int mm = 0; mm < 4; ++mm) {
        acc[mm][nn] = __builtin_amdgcn_mfma_f32_16x16x32_bf16(a[mm][0], b0, acc[mm][nn], 0, 0, 0);
        acc[mm][nn] = __builtin_amdgcn_mfma_f32_16x16x32_bf16(a[mm][1], b1, acc[mm][nn], 0, 0, 0);
      }
    }
  }
#pragma unroll
  for (int mm = 0; mm < 4; ++mm) {
#pragma unroll
    for (int r = 0; r < 4; ++r) {
      int mrow = mt * 128 + wr * 64 + mm * 16 + l4 * 4 + r;
      float* orow = out + (size_t)mrow * D_ + nt * 128 + wc * 64;
#pragma unroll
      for (int nn = 0; nn < 4; ++nn) {
        int n = nn * 16 + l15;
        orow[n] = acc[mm][nn][r] + bo[nt * 128 + wc * 64 + n];
      }
    }
  }
}

extern "C" void kernel_launch(void* const* d_in, const int* in_sizes, int n_in,
                              void* d_out, int out_size, void* d_ws, size_t ws_size,
                              hipStream_t stream) {
  const float* query = (const float*)d_in[0];
  const float* W_addr = (const float*)d_in[1];
  const float* b_addr = (const float*)d_in[2];
  const float* memory = (const float*)d_in[3];
  const float* W_out = (const float*)d_in[4];
  const float* b_out = (const float*)d_in[5];
  const float* Wq = (const float*)d_in[6];
  const float* bq = (const float*)d_in[7];
  const float* Wk = (const float*)d_in[8];
  const float* bk = (const float*)d_in[9];
  const float* Wv = (const float*)d_in[10];
  const float* bv = (const float*)d_in[11];
  const float* Wo = (const float*)d_in[12];
  const float* bo = (const float*)d_in[13];
  float* out = (float*)d_out;

  char* ws = (char*)d_ws;
  size_t off = 0;
  auto alloc = [&](size_t bytes) {
    char* p = ws + off;
    off = (off + bytes + 255) & ~(size_t)255;
    return p;
  };
  float* G = (float*)alloc(9 * D_ * sizeof(float));
  float* HqA = (float*)alloc(9 * D_ * sizeof(float));
  float* HkA = (float*)alloc(9 * D_ * sizeof(float));
  float* HvA = (float*)alloc(9 * D_ * sizeof(float));
  float* WaT = (float*)alloc(4 * D_ * sizeof(float));
  float* partmw = (float*)alloc(16 * J_ * D_ * sizeof(float));
  float* partq = (float*)alloc(3 * 4 * 9 * D_ * sizeof(float));
  unsigned short* WoT = (unsigned short*)alloc((size_t)D_ * D_ * 2);
  unsigned short* Vg = (unsigned short*)alloc((size_t)BH_ * S_ * HD_ * 2);
  unsigned short* Vtg = (unsigned short*)alloc((size_t)BH_ * S_ * HD_ * 2);
  unsigned short* Qg = (unsigned short*)d_out;
  unsigned short* Kg = Qg + (size_t)BH_ * S_ * HD_;
  unsigned short* ctx = Vg;

  k_mw_part<<<512, 256, 0, stream>>>(memory, W_out, Wo, partmw, WoT);
  k_mw_red<<<40, 256, 0, stream>>>(partmw, b_out, W_addr, G, WaT);
  k_mwq_part<<<192, 256, 0, stream>>>(G, Wq, Wk, Wv, partq);
  k_mwq_red<<<108, 256, 0, stream>>>(partq, bq, bk, bv, HqA, HkA, HvA);
  k_qkv<<<B_ * S_ / 4, 256, 0, stream>>>(query, WaT, b_addr, HqA, HkA, HvA,
                                         Qg, Kg, Vg);
  k_vt<<<BH_ * 32, 256, 0, stream>>>(Vg, Vtg);
  k_attn<<<1024, 512, 0, stream>>>(Qg, Kg, Vtg, ctx);
  k_out<<<dim3(64, 8), 256, 0, stream>>>(ctx, WoT, bo, out);
}

// Round 12
// 225.456 us; speedup vs baseline: 1.0439x; 1.0185x over previous
//
#include <hip/hip_runtime.h>

#define B_ 4
#define S_ 2048
#define D_ 1024
#define M_ 2048
#define J_ 8
#define H_ 16
#define HD_ 64
#define BH_ 64

typedef __attribute__((ext_vector_type(8))) short short8;
typedef __attribute__((ext_vector_type(4))) float f32x4;
typedef __attribute__((ext_vector_type(16))) float f32x16;

static __device__ __forceinline__ unsigned short f2bf(float x) {
  unsigned u = __float_as_uint(x);
  u = u + 0x7fffu + ((u >> 16) & 1u);
  return (unsigned short)(u >> 16);
}

static __device__ __forceinline__ unsigned cvtpk(float lo, float hi) {
  unsigned r;
  asm("v_cvt_pk_bf16_f32 %0, %1, %2" : "=v"(r) : "v"(lo), "v"(hi));
  return r;
}

static __device__ __forceinline__ void gload16(const void* g, void* l) {
  __builtin_amdgcn_global_load_lds(
      (const __attribute__((address_space(1))) unsigned*)g,
      (__attribute__((address_space(3))) unsigned*)l, 16, 0, 0);
}

// ---- memory @ W_out k-split partials (blocks 0..255) + WoT transpose (256..511)
__global__ __launch_bounds__(256) void k_mw_part(const float* __restrict__ memory,
                                                 const float* __restrict__ W_out,
                                                 const float* __restrict__ Wo,
                                                 float* __restrict__ part,
                                                 unsigned short* __restrict__ WoT) {
  if (blockIdx.x >= 256) {  // WoT[n][k] = bf16(Wo[k][n])
    int idx = blockIdx.x - 256;
    int kt = idx & 15, nt = idx >> 4;
    int t = threadIdx.x;
    __shared__ float tl[64][65];
    int r = t >> 6, c = t & 63;
#pragma unroll
    for (int i = 0; i < 16; ++i) {
      int row = i * 4 + r;
      tl[row][c] = Wo[(size_t)(kt * 64 + row) * D_ + nt * 64 + c];
    }
    __syncthreads();
#pragma unroll
    for (int i = 0; i < 16; ++i) {
      int nrow = i * 4 + r;
      WoT[(size_t)(nt * 64 + nrow) * D_ + kt * 64 + c] = f2bf(tl[c][nrow]);
    }
    return;
  }
  int nc = blockIdx.x >> 4, ks = blockIdx.x & 15;
  int t = threadIdx.x;
  int n = nc * 64 + (t & 63);
  int sub = t >> 6;
  int k0 = ks * 128 + sub * 32;
  float acc[J_];
#pragma unroll
  for (int j = 0; j < J_; ++j) acc[j] = 0.f;
  for (int k = k0; k < k0 + 32; ++k) {
    float wv = W_out[(size_t)k * D_ + n];
#pragma unroll
    for (int j = 0; j < J_; ++j) acc[j] += memory[j * M_ + k] * wv;
  }
  __shared__ float p4[4][J_][64];
#pragma unroll
  for (int j = 0; j < J_; ++j) p4[sub][j][t & 63] = acc[j];
  __syncthreads();
  if (t < 64) {
#pragma unroll
    for (int j = 0; j < J_; ++j)
      part[((size_t)ks * J_ + j) * D_ + nc * 64 + t] =
          p4[0][j][t] + p4[1][j][t] + p4[2][j][t] + p4[3][j][t];
  }
}

// G[9][1024] reduce + WaT[4][1024] = W_addr^T (cols 0..3 only)
__global__ __launch_bounds__(256) void k_mw_red(const float* __restrict__ part,
                                                const float* __restrict__ b_out,
                                                const float* __restrict__ W_addr,
                                                float* __restrict__ G,
                                                float* __restrict__ WaT) {
  if (blockIdx.x >= 36) {
    int q = blockIdx.x - 36;
    int c = threadIdx.x * 4;
#pragma unroll
    for (int e = 0; e < 4; ++e) WaT[q * D_ + c + e] = W_addr[(size_t)(c + e) * 16 + q];
    return;
  }
  int id = blockIdx.x * 256 + threadIdx.x;
  int j = id >> 10, n = id & 1023;
  if (j < 8) {
    float s = 0.f;
#pragma unroll
    for (int ks = 0; ks < 16; ++ks) s += part[((size_t)ks * J_ + j) * D_ + n];
    G[j * D_ + n] = s;
  } else {
    G[8 * D_ + n] = b_out[n];
  }
}

// G @ W_w, k-split partials: partq[3][4][9][1024]
__global__ __launch_bounds__(256) void k_mwq_part(const float* __restrict__ G,
                                                  const float* __restrict__ Wq,
                                                  const float* __restrict__ Wk,
                                                  const float* __restrict__ Wv,
                                                  float* __restrict__ partq) {
  int wi = blockIdx.x >> 6;
  int r = blockIdx.x & 63;
  int nc = r & 15, ks = r >> 4;
  const float* W = wi == 0 ? Wq : (wi == 1 ? Wk : Wv);
  int t = threadIdx.x;
  int n = nc * 64 + (t & 63);
  int sub = t >> 6;
  int k0 = ks * 256 + sub * 64;
  float acc[9];
#pragma unroll
  for (int j = 0; j < 9; ++j) acc[j] = 0.f;
  for (int k = k0; k < k0 + 64; ++k) {
    float wv = W[(size_t)k * D_ + n];
#pragma unroll
    for (int j = 0; j < 9; ++j) acc[j] += G[j * D_ + k] * wv;
  }
  __shared__ float p4[4][9][64];
#pragma unroll
  for (int j = 0; j < 9; ++j) p4[sub][j][t & 63] = acc[j];
  __syncthreads();
  if (t < 64) {
#pragma unroll
    for (int j = 0; j < 9; ++j)
      partq[(((size_t)wi * 4 + ks) * 9 + j) * D_ + nc * 64 + t] =
          p4[0][j][t] + p4[1][j][t] + p4[2][j][t] + p4[3][j][t];
  }
}

// reduce partials; fold bias into row 8 (no scaling — k_attn applies K1)
__global__ __launch_bounds__(256) void k_mwq_red(const float* __restrict__ partq,
                                                 const float* __restrict__ bq,
                                                 const float* __restrict__ bk,
                                                 const float* __restrict__ bv,
                                                 float* __restrict__ Hq,
                                                 float* __restrict__ Hk,
                                                 float* __restrict__ Hv) {
  int id = blockIdx.x * 256 + threadIdx.x;
  int wi = id / 9216;
  int rem = id - wi * 9216;
  int j = rem >> 10, n = rem & 1023;
  float s = 0.f;
#pragma unroll
  for (int ks = 0; ks < 4; ++ks)
    s += partq[(((size_t)wi * 4 + ks) * 9 + j) * D_ + n];
  if (j == 8) s += wi == 0 ? bq[n] : (wi == 1 ? bk[n] : bv[n]);
  float* Hh = wi == 0 ? Hq : (wi == 1 ? Hk : Hv);
  Hh[j * D_ + n] = s;
}

// wave-per-token QKV, fully coalesced reads (lane l: float4 at e*256+l*4).
// H* blended from global (L2-resident); bias pre-folded into row 8.
__global__ __launch_bounds__(256) void k_qkv(
    const float* __restrict__ query, const float* __restrict__ WaT,
    const float* __restrict__ b_addr, const float* __restrict__ Hq,
    const float* __restrict__ Hk, const float* __restrict__ Hv,
    unsigned short* __restrict__ Qg, unsigned short* __restrict__ Kg,
    unsigned short* __restrict__ Vg) {
  int w = threadIdx.x >> 6, l = threadIdx.x & 63;
  int tk = blockIdx.x * 4 + w;
  int b = tk >> 11, s = tk & (S_ - 1);
  const float* qrow = query + (size_t)tk * D_;
  float th0 = 0.f, th1 = 0.f, th2 = 0.f, th3 = 0.f;
#pragma unroll
  for (int e = 0; e < 4; ++e) {
    float4 qv = *(const float4*)(qrow + e * 256 + l * 4);
    float4 w0 = *(const float4*)(WaT + 0 * D_ + e * 256 + l * 4);
    float4 w1 = *(const float4*)(WaT + 1 * D_ + e * 256 + l * 4);
    float4 w2 = *(const float4*)(WaT + 2 * D_ + e * 256 + l * 4);
    float4 w3 = *(const float4*)(WaT + 3 * D_ + e * 256 + l * 4);
    th0 += qv.x * w0.x + qv.y * w0.y + qv.z * w0.z + qv.w * w0.w;
    th1 += qv.x * w1.x + qv.y * w1.y + qv.z * w1.z + qv.w * w1.w;
    th2 += qv.x * w2.x + qv.y * w2.y + qv.z * w2.z + qv.w * w2.w;
    th3 += qv.x * w3.x + qv.y * w3.y + qv.z * w3.z + qv.w * w3.w;
  }
#pragma unroll
  for (int off = 32; off; off >>= 1) {
    th0 += __shfl_xor(th0, off);
    th1 += __shfl_xor(th1, off);
    th2 += __shfl_xor(th2, off);
    th3 += __shfl_xor(th3, off);
  }
  float thv[4] = {th0 + b_addr[0], th1 + b_addr[1], th2 + b_addr[2],
                  th3 + b_addr[3]};
  float p[4];
#pragma unroll
  for (int q = 0; q < 4; ++q) {
    float sh = __sinf(thv[q] * 0.5f);
    p[q] = thv[q] > 0.f ? sh * sh : 0.f;
  }
  float sc[8];
  float mx = -1e30f;
#pragma unroll
  for (int j = 0; j < 8; ++j) {
    float v = 0.f;
#pragma unroll
    for (int q = 0; q < 4; ++q) v += ((j >> q) & 1) ? p[q] : 1.f - p[q];
    sc[j] = v;
    mx = fmaxf(mx, v);
  }
  float sum = 0.f;
#pragma unroll
  for (int j = 0; j < 8; ++j) {
    sc[j] = __expf(sc[j] - mx);
    sum += sc[j];
  }
  float inv = 1.f / sum;
  float a[8];
#pragma unroll
  for (int j = 0; j < 8; ++j) a[j] = sc[j] * inv;

  const float* Hs[3] = {Hq, Hk, Hv};
  unsigned short* os[3] = {Qg, Kg, Vg};
#pragma unroll
  for (int k = 0; k < 4; ++k) {
    int n0 = k * 256 + l * 4;
    int hh = n0 >> 6, d = n0 & 63;
    size_t obase = ((size_t)(b * H_ + hh) * S_ + s) * HD_ + d;
#pragma unroll
    for (int wi = 0; wi < 3; ++wi) {
      const float* Hh = Hs[wi];
      float4 accv = *(const float4*)(Hh + 8 * D_ + n0);  // bias pre-folded
#pragma unroll
      for (int j = 0; j < 8; ++j) {
        float4 hv = *(const float4*)(Hh + j * D_ + n0);
        accv.x += a[j] * hv.x;
        accv.y += a[j] * hv.y;
        accv.z += a[j] * hv.z;
        accv.w += a[j] * hv.w;
      }
      uint2 pk;
      pk.x = (unsigned)f2bf(accv.x) | ((unsigned)f2bf(accv.y) << 16);
      pk.y = (unsigned)f2bf(accv.z) | ((unsigned)f2bf(accv.w) << 16);
      *(uint2*)(os[wi] + obase) = pk;
    }
  }
}

// V (bh,s,d) -> Vt (bh,d,s)
__global__ __launch_bounds__(256) void k_vt(const unsigned short* __restrict__ Vg,
                                            unsigned short* __restrict__ Vtg) {
  int st = blockIdx.x & 31, bh = blockIdx.x >> 5;
  int t = threadIdx.x;
  __shared__ unsigned short tl[64][65];
  int rr = t >> 3, c8 = t & 7;
#pragma unroll
  for (int p = 0; p < 2; ++p) {
    int s = p * 32 + rr;
    uint4 v = *(const uint4*)(Vg + ((size_t)bh * S_ + st * 64 + s) * HD_ + c8 * 8);
    const unsigned short* pv = (const unsigned short*)&v;
#pragma unroll
    for (int j = 0; j < 8; ++j) tl[s][c8 * 8 + j] = pv[j];
  }
  __syncthreads();
#pragma unroll
  for (int p = 0; p < 2; ++p) {
    int d = p * 32 + rr;
    unsigned short o[8];
#pragma unroll
    for (int j = 0; j < 8; ++j) o[j] = tl[c8 * 8 + j][d];
    *(uint4*)(Vtg + ((size_t)bh * HD_ + d) * S_ + st * 64 + c8 * 8) = *(const uint4*)o;
  }
}

// flash attention: swapped-operand 32x32, in-block KV-split, fixed-max softmax
// (r9-proven inner loop), dbuf + issue-early global_load_lds, 1 barrier/tile.
__global__ __launch_bounds__(512, 4) void k_attn(
    const unsigned short* __restrict__ Qg, const unsigned short* __restrict__ Kg,
    const unsigned short* __restrict__ Vtg, unsigned short* __restrict__ ctxg) {
  int id = blockIdx.x;  // 1024 blocks
  int xcd = id & 7;
  int qt = (id >> 3) & 15;
  int bh = xcd * 8 + (id >> 7);  // 8 heads per XCD -> K/V 4MB = one L2
  int t = threadIdx.x;
  int w = t >> 6, l = t & 63;
  int q31 = l & 31, h = l >> 5;
  int g = w >> 2;  // kv-half

  __shared__ __align__(16) unsigned short lds[32768];

  int q0 = qt * 128;
  const unsigned short* qp = Qg + ((size_t)bh * S_ + q0 + (w & 3) * 32 + q31) * HD_;
  short8 qf0 = *(const short8*)(qp + 0 + h * 8);
  short8 qf1 = *(const short8*)(qp + 16 + h * 8);
  short8 qf2 = *(const short8*)(qp + 32 + h * 8);
  short8 qf3 = *(const short8*)(qp + 48 + h * 8);

  f32x16 accO0 = {}, accO1 = {};
  float lsum = 0.f;

  const unsigned short* kgb = Kg + (size_t)bh * S_ * HD_;
  const unsigned short* vtb = Vtg + (size_t)bh * HD_ * S_;
  int wg = w & 3;
  int rowK = l >> 3, gsl = l & 7;
  int srcg = gsl ^ rowK;

  {
    unsigned short* sKd = lds + g * 8192;
    unsigned short* sVd = sKd + 4096;
#pragma unroll
    for (int cc = 0; cc < 2; ++cc) {
      int c = wg * 2 + cc;
      int rr = c * 8 + rowK;
      gload16(kgb + ((size_t)(g * 1024 + rr)) * HD_ + srcg * 8, sKd + c * 512);
      gload16(vtb + (size_t)rr * S_ + g * 1024 + srcg * 8, sVd + c * 512);
    }
  }
  __syncthreads();

  const float K1 = 0.125f * 1.44269504f;
  const float M2 = 28.8539008f;  // 20 * log2(e): fixed softmax shift

  for (int it = 0; it < 16; ++it) {
    if (it < 15) {
      int kvn = g * 1024 + (it + 1) * 64;
      unsigned short* sKd = lds + ((it + 1) & 1) * 16384 + g * 8192;
      unsigned short* sVd = sKd + 4096;
#pragma unroll
      for (int cc = 0; cc < 2; ++cc) {
        int c = wg * 2 + cc;
        int rr = c * 8 + rowK;
        gload16(kgb + (size_t)(kvn + rr) * HD_ + srcg * 8, sKd + c * 512);
        gload16(vtb + (size_t)rr * S_ + kvn + srcg * 8, sVd + c * 512);
      }
    }
    unsigned short* sK = lds + (it & 1) * 16384 + g * 8192;
    unsigned short* sVt = sK + 4096;

    // QK^T: accS[half][r] = S'[kv][q = l&31]
    f32x16 accS0 = {}, accS1 = {};
    __builtin_amdgcn_s_setprio(1);
#pragma unroll
    for (int ds = 0; ds < 4; ++ds) {
      short8 qq = ds == 0 ? qf0 : ds == 1 ? qf1 : ds == 2 ? qf2 : qf3;
      {
        int row = q31;
        int gk = (ds * 2 + h) ^ (row & 7);
        short8 kf = *(const short8*)(sK + row * 64 + gk * 8);
        accS0 = __builtin_amdgcn_mfma_f32_32x32x16_bf16(kf, qq, accS0, 0, 0, 0);
      }
      {
        int row = 32 + q31;
        int gk = (ds * 2 + h) ^ (row & 7);
        short8 kf = *(const short8*)(sK + row * 64 + gk * 8);
        accS1 = __builtin_amdgcn_mfma_f32_32x32x16_bf16(kf, qq, accS1, 0, 0, 0);
      }
    }
    __builtin_amdgcn_s_setprio(0);

    // fixed-max softmax: P = exp2(S*K1 - M2); lane-local lsum
    float ts = 0.f;
#pragma unroll
    for (int r = 0; r < 16; ++r) {
      float p0 = __builtin_exp2f(accS0[r] * K1 - M2);
      float p1 = __builtin_exp2f(accS1[r] * K1 - M2);
      accS0[r] = p0;
      accS1[r] = p1;
      ts += p0 + p1;
    }
    lsum += ts;

    // P -> bf16 B-fragments
    short8 pb[4];
#pragma unroll
    for (int ks = 0; ks < 4; ++ks) {
      const int r0 = 8 * (ks & 1);
      float v0, v1, v2, v3, v4, v5, v6, v7;
      if (ks < 2) {
        v0 = accS0[r0 + 0]; v1 = accS0[r0 + 1]; v2 = accS0[r0 + 2]; v3 = accS0[r0 + 3];
        v4 = accS0[r0 + 4]; v5 = accS0[r0 + 5]; v6 = accS0[r0 + 6]; v7 = accS0[r0 + 7];
      } else {
        v0 = accS1[r0 + 0]; v1 = accS1[r0 + 1]; v2 = accS1[r0 + 2]; v3 = accS1[r0 + 3];
        v4 = accS1[r0 + 4]; v5 = accS1[r0 + 5]; v6 = accS1[r0 + 6]; v7 = accS1[r0 + 7];
      }
      unsigned X0 = cvtpk(v0, v1), X1 = cvtpk(v2, v3);
      unsigned Y0 = cvtpk(v4, v5), Y1 = cvtpk(v6, v7);
      union { unsigned u[4]; short8 s8; } uu;
#if __has_builtin(__builtin_amdgcn_permlane32_swap)
      typedef __attribute__((ext_vector_type(2))) unsigned uint2v;
      uint2v r02 = __builtin_amdgcn_permlane32_swap(X0, Y0, false, false);
      uint2v r13 = __builtin_amdgcn_permlane32_swap(X1, Y1, false, false);
      uu.u[0] = r02[0]; uu.u[1] = r13[0]; uu.u[2] = r02[1]; uu.u[3] = r13[1];
#else
      unsigned tX0 = __shfl_xor(X0, 32), tX1 = __shfl_xor(X1, 32);
      unsigned tY0 = __shfl_xor(Y0, 32), tY1 = __shfl_xor(Y1, 32);
      uu.u[0] = h ? tY0 : X0;
      uu.u[1] = h ? tY1 : X1;
      uu.u[2] = h ? Y0 : tX0;
      uu.u[3] = h ? Y1 : tX1;
#endif
      pb[ks] = uu.s8;
    }

    // PV
    __builtin_amdgcn_s_setprio(1);
    {
      int row = q31;
      int rs = row & 7;
#pragma unroll
      for (int ks = 0; ks < 4; ++ks) {
        int gv = (ks * 2 + h) ^ rs;
        short8 vf = *(const short8*)(sVt + row * 64 + gv * 8);
        accO0 = __builtin_amdgcn_mfma_f32_32x32x16_bf16(vf, pb[ks], accO0, 0, 0, 0);
      }
    }
    {
      int row = 32 + q31;
      int rs = row & 7;
#pragma unroll
      for (int ks = 0; ks < 4; ++ks) {
        int gv = (ks * 2 + h) ^ rs;
        short8 vf = *(const short8*)(sVt + row * 64 + gv * 8);
        accO1 = __builtin_amdgcn_mfma_f32_32x32x16_bf16(vf, pb[ks], accO1, 0, 0, 0);
      }
    }
    __builtin_amdgcn_s_setprio(0);

    __syncthreads();
  }

  float lt = lsum + __shfl_xor(lsum, 32);

  // in-block combine: waves 4-7 hand (lsum, unnormalized accO) to 0-3
  if (g == 1) {
    unsigned* xO = (unsigned*)lds;  // [4][64][17] u32
    int base = ((w & 3) * 64 + l) * 17;
#pragma unroll
    for (int j = 0; j < 8; ++j) xO[base + j] = cvtpk(accO0[2 * j], accO0[2 * j + 1]);
#pragma unroll
    for (int j = 0; j < 8; ++j) xO[base + 8 + j] = cvtpk(accO1[2 * j], accO1[2 * j + 1]);
    float* xml = (float*)(lds + 8704);
    if (h == 0) xml[(w & 3) * 32 + q31] = lt;
  }
  __syncthreads();
  float inv = 0.f;
  if (g == 0) {
    unsigned* xO = (unsigned*)lds;
    float* xml = (float*)(lds + 8704);
    int base = (w * 64 + l) * 17;
    inv = 1.f / (lt + xml[w * 32 + q31]);
#pragma unroll
    for (int j = 0; j < 8; ++j) {
      unsigned wd = xO[base + j];
      accO0[2 * j] += __uint_as_float(wd << 16);
      accO0[2 * j + 1] += __uint_as_float(wd & 0xffff0000u);
    }
#pragma unroll
    for (int j = 0; j < 8; ++j) {
      unsigned wd = xO[base + 8 + j];
      accO1[2 * j] += __uint_as_float(wd << 16);
      accO1[2 * j + 1] += __uint_as_float(wd & 0xffff0000u);
    }
  }
  __syncthreads();
  if (g == 0) {
    int row = w * 32 + q31;
    int swz = (q31 & 7) << 3;
#pragma unroll
    for (int r = 0; r < 16; ++r) {
      int dl = (r & 3) + 8 * (r >> 2) + 4 * h;
      lds[row * 64 + (dl ^ swz)] = f2bf(accO0[r] * inv);
      lds[row * 64 + ((32 + dl) ^ swz)] = f2bf(accO1[r] * inv);
    }
  }
  __syncthreads();
  int b = bh >> 4, head = bh & 15;
#pragma unroll
  for (int j = 0; j < 2; ++j) {
    int slot = t + j * 512;
    int row = slot >> 3, gg = slot & 7;
    uint4 vv = *(const uint4*)(lds + row * 64 + ((gg ^ (row & 7)) * 8));
    *(uint4*)(ctxg + ((size_t)(b * S_ + q0 + row)) * D_ + head * HD_ + gg * 8) = vv;
  }
}

// out[8192,1024] = ctx @ Wo + bo
// double-buffered gload16 staging, issue-early, ONE barrier per K-step.
__global__ __launch_bounds__(256) void k_out(const unsigned short* __restrict__ Ag,
                                             const unsigned short* __restrict__ Btg,
                                             const float* __restrict__ bo,
                                             float* __restrict__ out) {
  int mt = blockIdx.x;
  int nt = blockIdx.y;
  int t = threadIdx.x;
  int w = t >> 6, l = t & 63;
  int l15 = l & 15, l4 = l >> 4;
  int wr = w >> 1, wc = w & 1;
  // [2 bufs][sA 8192 | sB 8192] shorts = 64KB
  __shared__ __align__(16) unsigned short lds[32768];
  f32x4 acc[4][4];
#pragma unroll
  for (int mm = 0; mm < 4; ++mm)
#pragma unroll
    for (int nn = 0; nn < 4; ++nn) acc[mm][nn] = (f32x4){0.f, 0.f, 0.f, 0.f};
  int srow = t >> 3, gsl = t & 7;
  int srcg = gsl ^ (srow & 7);  // inverse-swizzled source granule (rule #21)

  {  // prologue: stage kt=0 into buf 0
    unsigned short* sA = lds;
    unsigned short* sB = lds + 8192;
#pragma unroll
    for (int p = 0; p < 4; ++p) {
      int row = p * 32 + srow;
      gload16(Ag + (size_t)(mt * 128 + row) * D_ + srcg * 8, sA + (p * 256 + t) * 8);
      gload16(Btg + (size_t)(nt * 128 + row) * D_ + srcg * 8, sB + (p * 256 + t) * 8);
    }
  }
  __syncthreads();

  for (int kt = 0; kt < 16; ++kt) {
    if (kt < 15) {  // issue-early stage of kt+1 into the other buffer
      int k0n = (kt + 1) * 64;
      unsigned short* sA = lds + ((kt + 1) & 1) * 16384;
      unsigned short* sB = sA + 8192;
#pragma unroll
      for (int p = 0; p < 4; ++p) {
        int row = p * 32 + srow;
        gload16(Ag + (size_t)(mt * 128 + row) * D_ + k0n + srcg * 8,
                sA + (p * 256 + t) * 8);
        gload16(Btg + (size_t)(nt * 128 + row) * D_ + k0n + srcg * 8,
                sB + (p * 256 + t) * 8);
      }
    }
    const unsigned short* sA = lds + (kt & 1) * 16384;
    const unsigned short* sB = sA + 8192;
    short8 a[4][2];
#pragma unroll
    for (int mm = 0; mm < 4; ++mm) {
      int row = wr * 64 + mm * 16 + l15;
      int sw = (row & 7) << 3;
      a[mm][0] = *(const short8*)(sA + row * 64 + ((l4 * 8) ^ sw));
      a[mm][1] = *(const short8*)(sA + row * 64 + ((32 + l4 * 8) ^ sw));
    }
#pragma unroll
    for (int nn = 0; nn < 4; ++nn) {
      int row = wc * 64 + nn * 16 + l15;
      int sw = (row & 7) << 3;
      short8 b0 = *(const short8*)(sB + row * 64 + ((l4 * 8) ^ sw));
      short8 b1 = *(const short8*)(sB + row * 64 + ((32 + l4 * 8) ^ sw));
#pragma unroll
      for (int mm = 0; mm < 4; ++mm) {
        acc[mm][nn] = __builtin_amdgcn_mfma_f32_16x16x32_bf16(a[mm][0], b0, acc[mm][nn], 0, 0, 0);
        acc[mm][nn] = __builtin_amdgcn_mfma_f32_16x16x32_bf16(a[mm][1], b1, acc[mm][nn], 0, 0, 0);
      }
    }
    __syncthreads();  // drains prefetch vmcnt + guards buffer reuse
  }
#pragma unroll
  for (int mm = 0; mm < 4; ++mm) {
#pragma unroll
    for (int r = 0; r < 4; ++r) {
      int mrow = mt * 128 + wr * 64 + mm * 16 + l4 * 4 + r;
      float* orow = out + (size_t)mrow * D_ + nt * 128 + wc * 64;
#pragma unroll
      for (int nn = 0; nn < 4; ++nn) {
        int n = nn * 16 + l15;
        orow[n] = acc[mm][nn][r] + bo[nt * 128 + wc * 64 + n];
      }
    }
  }
}

extern "C" void kernel_launch(void* const* d_in, const int* in_sizes, int n_in,
                              void* d_out, int out_size, void* d_ws, size_t ws_size,
                              hipStream_t stream) {
  const float* query = (const float*)d_in[0];
  const float* W_addr = (const float*)d_in[1];
  const float* b_addr = (const float*)d_in[2];
  const float* memory = (const float*)d_in[3];
  const float* W_out = (const float*)d_in[4];
  const float* b_out = (const float*)d_in[5];
  const float* Wq = (const float*)d_in[6];
  const float* bq = (const float*)d_in[7];
  const float* Wk = (const float*)d_in[8];
  const float* bk = (const float*)d_in[9];
  const float* Wv = (const float*)d_in[10];
  const float* bv = (const float*)d_in[11];
  const float* Wo = (const float*)d_in[12];
  const float* bo = (const float*)d_in[13];
  float* out = (float*)d_out;

  char* ws = (char*)d_ws;
  size_t off = 0;
  auto alloc = [&](size_t bytes) {
    char* p = ws + off;
    off = (off + bytes + 255) & ~(size_t)255;
    return p;
  };
  float* G = (float*)alloc(9 * D_ * sizeof(float));
  float* HqA = (float*)alloc(9 * D_ * sizeof(float));
  float* HkA = (float*)alloc(9 * D_ * sizeof(float));
  float* HvA = (float*)alloc(9 * D_ * sizeof(float));
  float* WaT = (float*)alloc(4 * D_ * sizeof(float));
  float* partmw = (float*)alloc(16 * J_ * D_ * sizeof(float));
  float* partq = (float*)alloc(3 * 4 * 9 * D_ * sizeof(float));
  unsigned short* WoT = (unsigned short*)alloc((size_t)D_ * D_ * 2);
  unsigned short* Vg = (unsigned short*)alloc((size_t)BH_ * S_ * HD_ * 2);
  unsigned short* Vtg = (unsigned short*)alloc((size_t)BH_ * S_ * HD_ * 2);
  unsigned short* Qg = (unsigned short*)d_out;
  unsigned short* Kg = Qg + (size_t)BH_ * S_ * HD_;
  unsigned short* ctx = Vg;

  k_mw_part<<<512, 256, 0, stream>>>(memory, W_out, Wo, partmw, WoT);
  k_mw_red<<<40, 256, 0, stream>>>(partmw, b_out, W_addr, G, WaT);
  k_mwq_part<<<192, 256, 0, stream>>>(G, Wq, Wk, Wv, partq);
  k_mwq_red<<<108, 256, 0, stream>>>(partq, bq, bk, bv, HqA, HkA, HvA);
  k_qkv<<<B_ * S_ / 4, 256, 0, stream>>>(query, WaT, b_addr, HqA, HkA, HvA,
                                         Qg, Kg, Vg);
  k_vt<<<BH_ * 32, 256, 0, stream>>>(Vg, Vtg);
  k_attn<<<1024, 512, 0, stream>>>(Qg, Kg, Vtg, ctx);
  k_out<<<dim3(64, 8), 256, 0, stream>>>(ctx, WoT, bo, out);
}